// Round 8
// baseline (595.631 us; speedup 1.0000x reference)
//
#include <hip/hip_runtime.h>
#include <hip/hip_bf16.h>
#include <math.h>

// ---------------------------------------------------------------------------
// GRU-like cell. B=64, T=512, D=512, H=1024 (fp32).
// Round 9 (= round 8 with the XI allocation-size bug fixed):
//   * Theory: scan capped at ~2 TB/s by DRAM burst granularity: each block
//     read only 1KB per 4KB row per t, the rest of the row touched by other
//     CUs at drifted times -> per-piece row activations.
//   * Fix: gate-sliced intermediate layout XI[b][h_hi][t][3][256]
//     (h_hi = h>>8). Each 256-thread block owns slice (b,h_hi) and reads
//     3KB contiguous per t -> 48KB sequential stream per 16-step chunk.
//     GEMM epilogue stores this layout directly (verified bijective).
//   * R7 BUG: XI_BYTES was M_DIM*GS*4 (100MB) but XI spans M_DIM*N3*4
//     (402MB) -> XHI/XLO/WTH/WTL overlapped XI -> GEMM inputs overwritten
//     mid-kernel -> NaN. Fixed: XI_BYTES = M_DIM*N3*4.
//   * Scan math bit-identical to round 3 (rcp+NR sigmoid form, absmax 2^-8).
// Precision: 3-term fp16 split GEMM and fp32 scan math unchanged.
// ---------------------------------------------------------------------------

#define M_DIM 32768   // B*T
#define K_DIM 512     // D
#define H_DIM 1024
#define N3    3072    // 3*H
#define GS    768     // gate-sliced row: 3*256 floats per (b,hh,t)

typedef _Float16 half8v __attribute__((ext_vector_type(8)));
typedef _Float16 half4v __attribute__((ext_vector_type(4)));
typedef float f32x4 __attribute__((ext_vector_type(4)));

__device__ __forceinline__ f32x4 mfma16(half8v a, half8v b, f32x4 c) {
    return __builtin_amdgcn_mfma_f32_16x16x32_f16(a, b, c, 0, 0, 0);
}

__device__ __forceinline__ void load_lds16(const void* g, void* l) {
    __builtin_amdgcn_global_load_lds(
        (const __attribute__((address_space(1))) void*)g,
        (__attribute__((address_space(3))) void*)l, 16, 0, 0);
}

// ---------------------------------------------------------------------------
// Conversion: x [M,K] fp32 -> xhi/xlo fp16 (same layout), via float4.
// ---------------------------------------------------------------------------
__global__ __launch_bounds__(256) void convert_x(
    const float4* __restrict__ x4, half4v* __restrict__ hi4,
    half4v* __restrict__ lo4, int n4)
{
    int i = blockIdx.x * 256 + threadIdx.x;
    if (i >= n4) return;
    float4 v = x4[i];
    half4v h, lo;
    h.x = (_Float16)v.x; lo.x = (_Float16)(v.x - (float)h.x);
    h.y = (_Float16)v.y; lo.y = (_Float16)(v.y - (float)h.y);
    h.z = (_Float16)v.z; lo.z = (_Float16)(v.z - (float)h.z);
    h.w = (_Float16)v.w; lo.w = (_Float16)(v.w - (float)h.w);
    hi4[i] = h; lo4[i] = lo;
}

// ---------------------------------------------------------------------------
// Weights [K,1024] fp32 -> transposed hi/lo fp16 [3][1024][512].
// LDS-tiled 64x64 transpose: coalesced reads AND writes.
// ---------------------------------------------------------------------------
__global__ __launch_bounds__(256) void convert_wt_t(
    const float* __restrict__ kz, const float* __restrict__ kr,
    const float* __restrict__ kh, _Float16* __restrict__ wth,
    _Float16* __restrict__ wtl)
{
    __shared__ float lds[64][65];
    const int bid = blockIdx.x;          // 3 * 8 * 16 = 384
    const int w = bid >> 7;              // weight select
    const int rem = bid & 127;
    const int k0 = (rem >> 4) * 64;
    const int n0 = (rem & 15) * 64;
    const int tid = threadIdx.x;
    const float* s = (w == 0) ? kz : ((w == 1) ? kr : kh);

#pragma unroll
    for (int r = 0; r < 4; ++r) {
        const int kk = (tid >> 4) + r * 16;
        const int nn = (tid & 15) * 4;
        float4 v = *(const float4*)&s[(size_t)(k0 + kk) * H_DIM + n0 + nn];
        lds[kk][nn + 0] = v.x; lds[kk][nn + 1] = v.y;
        lds[kk][nn + 2] = v.z; lds[kk][nn + 3] = v.w;
    }
    __syncthreads();
#pragma unroll
    for (int r = 0; r < 4; ++r) {
        const int nr = (tid >> 4) + r * 16;
        const int kb = (tid & 15) * 4;
        half4v hi, lo;
#pragma unroll
        for (int i = 0; i < 4; ++i) {
            float v = lds[kb + i][nr];
            _Float16 h = (_Float16)v;
            hi[i] = h; lo[i] = (_Float16)(v - (float)h);
        }
        const size_t o = ((size_t)(w * H_DIM + n0 + nr)) * K_DIM + k0 + kb;
        *(half4v*)&wth[o] = hi;
        *(half4v*)&wtl[o] = lo;
    }
}

// ---------------------------------------------------------------------------
// MFMA GEMM: C[M,3072] = A[M,512] * Bt[3072,512]^T with fp16 3-term split.
// Round-0 structure verbatim: 128x128 block tile, 4 waves each 64x64.
// LAYOUT=0: three separate dsts, row stride H_DIM (mid-tier path).
// LAYOUT=1: gate-sliced XI[b][hh][t][3][256]; XZ arg = XI, XR/OUT unused.
// ---------------------------------------------------------------------------
template<int LAYOUT>
__global__ __launch_bounds__(256) void gemm_mfma_split(
    const _Float16* __restrict__ Ahi, const _Float16* __restrict__ Alo,
    const _Float16* __restrict__ Bthi, const _Float16* __restrict__ Btlo,
    float* __restrict__ XZ, float* __restrict__ XR, float* __restrict__ OUT)
{
    __shared__ _Float16 Ah[128 * 32];
    __shared__ _Float16 Al[128 * 32];
    __shared__ _Float16 Bh[128 * 32];
    __shared__ _Float16 Bl[128 * 32];

    const int tid = threadIdx.x;
    const int w = tid >> 6, l = tid & 63;
    const int l15 = l & 15, quad = l >> 4;
    const int bx = blockIdx.x, by = blockIdx.y;
    const long m0 = (long)by * 128;
    const long n0 = (long)bx * 128;

    f32x4 acc[4][4] = {};

    // staging: 512 16B-slots per tile, thread covers slots tid and tid+256.
    const int s1 = tid, s2 = tid + 256;
    const long aoff1 = (m0 + (s1 >> 2)) * K_DIM + (s1 & 3) * 8;
    const long aoff2 = (m0 + (s2 >> 2)) * K_DIM + (s2 & 3) * 8;
    const long boff1 = (n0 + (s1 >> 2)) * K_DIM + (s1 & 3) * 8;
    const long boff2 = (n0 + (s2 >> 2)) * K_DIM + (s2 & 3) * 8;

    const _Float16* a1 = Ahi + aoff1;  const _Float16* a2 = Ahi + aoff2;
    const _Float16* q1 = Alo + aoff1;  const _Float16* q2 = Alo + aoff2;
    const _Float16* b1 = Bthi + boff1; const _Float16* b2 = Bthi + boff2;
    const _Float16* c1 = Btlo + boff1; const _Float16* c2 = Btlo + boff2;

    _Float16* ldsA1 = &Ah[w * 512]; _Float16* ldsA2 = &Ah[2048 + w * 512];
    _Float16* ldsQ1 = &Al[w * 512]; _Float16* ldsQ2 = &Al[2048 + w * 512];
    _Float16* ldsB1 = &Bh[w * 512]; _Float16* ldsB2 = &Bh[2048 + w * 512];
    _Float16* ldsC1 = &Bl[w * 512]; _Float16* ldsC2 = &Bl[2048 + w * 512];

    const int wm = (w >> 1) * 64, wn = (w & 1) * 64;

    for (int kk = 0; kk < K_DIM / 32; ++kk) {
        load_lds16(a1, ldsA1); load_lds16(a2, ldsA2);
        load_lds16(q1, ldsQ1); load_lds16(q2, ldsQ2);
        load_lds16(b1, ldsB1); load_lds16(b2, ldsB2);
        load_lds16(c1, ldsC1); load_lds16(c2, ldsC2);
        a1 += 32; a2 += 32; q1 += 32; q2 += 32;
        b1 += 32; b2 += 32; c1 += 32; c2 += 32;
        __syncthreads();

        half8v afh[4], afl[4], bfh[4], bfl[4];
#pragma unroll
        for (int mi = 0; mi < 4; ++mi) {
            int row = (wm + mi * 16 + l15) * 32 + quad * 8;
            afh[mi] = *(const half8v*)&Ah[row];
            afl[mi] = *(const half8v*)&Al[row];
        }
#pragma unroll
        for (int ni = 0; ni < 4; ++ni) {
            int row = (wn + ni * 16 + l15) * 32 + quad * 8;
            bfh[ni] = *(const half8v*)&Bh[row];
            bfl[ni] = *(const half8v*)&Bl[row];
        }
#pragma unroll
        for (int mi = 0; mi < 4; ++mi)
#pragma unroll
            for (int ni = 0; ni < 4; ++ni) {
                acc[mi][ni] = mfma16(afh[mi], bfh[ni], acc[mi][ni]);
                acc[mi][ni] = mfma16(afh[mi], bfl[ni], acc[mi][ni]);
                acc[mi][ni] = mfma16(afl[mi], bfh[ni], acc[mi][ni]);
            }
        __syncthreads();
    }

    // Epilogue: C/D layout col=lane&15, row=quad*4+i.
    if (LAYOUT == 0) {
        float* dst = (bx < 8) ? XZ : ((bx < 16) ? XR : OUT);
        const long nl = (long)(bx & 7) * 128 + wn + l15;
#pragma unroll
        for (int mi = 0; mi < 4; ++mi) {
            const long m = m0 + wm + mi * 16 + quad * 4;
#pragma unroll
            for (int ni = 0; ni < 4; ++ni) {
                float* p = dst + m * H_DIM + nl + ni * 16;
#pragma unroll
                for (int i = 0; i < 4; ++i)
                    p[(long)i * H_DIM] = acc[mi][ni][i];
            }
        }
    } else {
        // Gate-sliced: XI[b][hh][t][gate][256]; n>>8 constant per tile
        // (nlo+ni*16 <= 255, never carries into hh).
        float* XI = XZ;
        const int gate = bx >> 3;                    // 0=z 1=r 2=h
        const long n   = (long)(bx & 7) * 128 + wn + l15;
        const long hh  = n >> 8;
        const long nlo = n & 255;
#pragma unroll
        for (int mi = 0; mi < 4; ++mi) {
            const long m = m0 + wm + mi * 16 + quad * 4;
            const long b = m >> 9;
            const long t = m & 511;
            float* p = XI + ((b * 4 + hh) * 512 + t) * GS + gate * 256 + nlo;
#pragma unroll
            for (int ni = 0; ni < 4; ++ni) {
#pragma unroll
                for (int i = 0; i < 4; ++i)
                    p[(long)i * GS + ni * 16] = acc[mi][ni][i];
            }
        }
    }
}

// ---------------------------------------------------------------------------
// Fallback fp32 GEMM (round 0)
// ---------------------------------------------------------------------------
#define BM 128
#define BN 128
#define BK 8
__global__ __launch_bounds__(256) void gemm_f32(
    const float* __restrict__ A, const float* __restrict__ B,
    float* __restrict__ C, int M, int N, int K)
{
    __shared__ float As[BK][BM];
    __shared__ float Bs[BK][BN];
    const int tid = threadIdx.x;
    const int bm = blockIdx.y * BM, bn = blockIdx.x * BN;
    const int tx = tid & 15, ty = tid >> 4;
    float acc[8][8];
#pragma unroll
    for (int i = 0; i < 8; i++)
#pragma unroll
        for (int j = 0; j < 8; j++) acc[i][j] = 0.f;
    const int a_row = tid >> 1, a_k = (tid & 1) * 4;
    const int b_row = tid >> 5, b_col = (tid & 31) * 4;
    const float* Aptr = A + (size_t)(bm + a_row) * K + a_k;
    const float* Bptr = B + (size_t)b_row * N + bn + b_col;
    for (int k0 = 0; k0 < K; k0 += BK) {
        float4 av = *(const float4*)(Aptr + k0);
        float4 bv = *(const float4*)(Bptr + (size_t)k0 * N);
        As[a_k + 0][a_row] = av.x; As[a_k + 1][a_row] = av.y;
        As[a_k + 2][a_row] = av.z; As[a_k + 3][a_row] = av.w;
        *(float4*)&Bs[b_row][b_col] = bv;
        __syncthreads();
#pragma unroll
        for (int kk = 0; kk < BK; kk++) {
            float4 a0 = *(const float4*)&As[kk][ty * 8];
            float4 a1 = *(const float4*)&As[kk][ty * 8 + 4];
            float4 b0 = *(const float4*)&Bs[kk][tx * 8];
            float4 b1 = *(const float4*)&Bs[kk][tx * 8 + 4];
            float a[8] = {a0.x, a0.y, a0.z, a0.w, a1.x, a1.y, a1.z, a1.w};
            float b[8] = {b0.x, b0.y, b0.z, b0.w, b1.x, b1.y, b1.z, b1.w};
#pragma unroll
            for (int i = 0; i < 8; i++)
#pragma unroll
                for (int j = 0; j < 8; j++)
                    acc[i][j] = fmaf(a[i], b[j], acc[i][j]);
        }
        __syncthreads();
    }
    float* Cptr = C + (size_t)(bm + ty * 8) * N + bn + tx * 8;
#pragma unroll
    for (int i = 0; i < 8; i++) {
        float4 c0 = {acc[i][0], acc[i][1], acc[i][2], acc[i][3]};
        float4 c1 = {acc[i][4], acc[i][5], acc[i][6], acc[i][7]};
        *(float4*)(Cptr + (size_t)i * N)     = c0;
        *(float4*)(Cptr + (size_t)i * N + 4) = c1;
    }
}

// ---------------------------------------------------------------------------
// Scan math (shared): gates in sigmoid form; divisions via v_rcp + 1 Newton.
// ---------------------------------------------------------------------------
__device__ __forceinline__ float vrcp_nr(float d) {
    float r = __builtin_amdgcn_rcpf(d);
    return r * fmaf(-d, r, 2.0f);     // Newton: r*(2 - d*r)
}

// ---------------------------------------------------------------------------
// Gate-sliced scan: block (b,hh) streams XI[b][hh][t][3][256] sequentially
// (3KB contiguous per t, 48KB per 16-step chunk, exclusively owned).
// Math identical to round 3. Writes out[b][t][h].
// ---------------------------------------------------------------------------
__global__ __launch_bounds__(256) void scan_gs(
    const float* __restrict__ XI, float* __restrict__ out,
    const float* __restrict__ mz, const float* __restrict__ mr,
    const float* __restrict__ br, const float* __restrict__ bz)
{
    const int bid = blockIdx.x;            // 256 = 64 b * 4 hh
    const int b = bid >> 2, hh = bid & 3;
    const int tid = threadIdx.x;
    const int h = hh * 256 + tid;

    const float mzK = -mz[h];
    const float mrK = -2.0f * mr[h];
    const float bzK = -bz[h];
    const float brK = -2.0f * br[h];
    float hs = 0.f;

    const float* base = XI + ((size_t)(b * 4 + hh) * 512) * GS + tid;
    float* const po = out + ((size_t)b << 19) + h;     // b*512*1024 + h

    float cz[16], cr[16], ch[16];
#pragma unroll
    for (int j = 0; j < 16; ++j) {
        const float* p = base + (size_t)j * GS;
        cz[j] = bzK - p[0];
        cr[j] = fmaf(-2.0f, p[256], brK);
        ch[j] = -2.0f * p[512];
    }
    for (int t0 = 0; t0 < 512; t0 += 16) {
        float nz[16], nr[16], nh[16];
        const bool more = (t0 + 16) < 512;
        if (more) {
            const float* pb = base + (size_t)(t0 + 16) * GS;
#pragma unroll
            for (int j = 0; j < 16; ++j) {
                const float* p = pb + (size_t)j * GS;
                nz[j] = p[0]; nr[j] = p[256]; nh[j] = p[512];
            }
        }
        float* pout = po + ((size_t)t0 << 10);
#pragma unroll
        for (int j = 0; j < 16; ++j) {
            const float u1   = fmaf(hs, mrK, cr[j]);
            const float uz   = fmaf(hs, mzK, cz[j]);
            const float hsK2 = -4.0f * hs;
            const float e1 = __expf(u1);
            const float s1 = vrcp_nr(e1 + 1.0f);
            const float ez = __expf(uz);
            const float sz = vrcp_nr(ez + 1.0f);
            const float u2 = fmaf(s1, hsK2, ch[j]);
            const float e2 = __expf(u2);
            const float s2 = vrcp_nr(e2 + 1.0f);
            const float th = fmaf(2.0f, s2, -1.0f);
            const float hn = fmaf(sz, hs - th, th);
            *pout = hn; pout += H_DIM;
            hs = hn;
        }
        if (more) {
#pragma unroll
            for (int j = 0; j < 16; ++j) {
                cz[j] = bzK - nz[j];
                cr[j] = fmaf(-2.0f, nr[j], brK);
                ch[j] = -2.0f * nh[j];
            }
        }
    }
}

// ---------------------------------------------------------------------------
// OLD scan (round 3), unpadded in-place variant for the mid-tier path.
// ---------------------------------------------------------------------------
__global__ __launch_bounds__(256) void scan_kernel(
    const float* __restrict__ XZ, const float* __restrict__ XR,
    float* __restrict__ OUT,
    const float* __restrict__ mz, const float* __restrict__ mr,
    const float* __restrict__ br, const float* __restrict__ bz)
{
    const int gid = blockIdx.x * blockDim.x + threadIdx.x;
    const int b = gid >> 10;
    const int h = gid & (H_DIM - 1);

    const float mzK = -mz[h];
    const float mrK = -2.0f * mr[h];
    const float bzK = -bz[h];
    const float brK = -2.0f * br[h];
    float hs = 0.f;
    size_t idx = (size_t)b * 512 * H_DIM + h;

    float cz[16], cr[16], ch[16];
#pragma unroll
    for (int j = 0; j < 16; ++j) {
        cz[j] = bzK - XZ[idx + (size_t)j * H_DIM];
        cr[j] = fmaf(-2.0f, XR[idx + (size_t)j * H_DIM], brK);
        ch[j] = -2.0f * OUT[idx + (size_t)j * H_DIM];
    }
    for (int t0 = 0; t0 < 512; t0 += 16) {
        float nz[16], nr[16], nh[16];
        const bool more = (t0 + 16) < 512;
        const size_t nidx = idx + 16ul * H_DIM;
        if (more) {
#pragma unroll
            for (int j = 0; j < 16; ++j) {
                nz[j] = XZ[nidx + (size_t)j * H_DIM];
                nr[j] = XR[nidx + (size_t)j * H_DIM];
                nh[j] = OUT[nidx + (size_t)j * H_DIM];
            }
        }
#pragma unroll
        for (int j = 0; j < 16; ++j) {
            const float u1   = fmaf(hs, mrK, cr[j]);
            const float uz   = fmaf(hs, mzK, cz[j]);
            const float hsK2 = -4.0f * hs;
            const float e1 = __expf(u1);
            const float s1 = vrcp_nr(e1 + 1.0f);
            const float ez = __expf(uz);
            const float sz = vrcp_nr(ez + 1.0f);
            const float u2 = fmaf(s1, hsK2, ch[j]);
            const float e2 = __expf(u2);
            const float s2 = vrcp_nr(e2 + 1.0f);
            const float th = fmaf(2.0f, s2, -1.0f);
            const float hn = fmaf(sz, hs - th, th);
            OUT[idx + (size_t)j * H_DIM] = hn;
            hs = hn;
        }
        idx = nidx;
        if (more) {
#pragma unroll
            for (int j = 0; j < 16; ++j) {
                cz[j] = bzK - nz[j];
                cr[j] = fmaf(-2.0f, nr[j], brK);
                ch[j] = -2.0f * nh[j];
            }
        }
    }
}

// ---------------------------------------------------------------------------
extern "C" void kernel_launch(void* const* d_in, const int* in_sizes, int n_in,
                              void* d_out, int out_size, void* d_ws, size_t ws_size,
                              hipStream_t stream) {
    const float* x  = (const float*)d_in[0];
    const float* kz = (const float*)d_in[1];
    const float* kr = (const float*)d_in[2];
    const float* kh = (const float*)d_in[3];
    const float* mz = (const float*)d_in[4];
    const float* mr = (const float*)d_in[5];
    const float* br = (const float*)d_in[6];
    const float* bz = (const float*)d_in[7];
    float* out = (float*)d_out;

    char* ws = (char*)d_ws;
    const int n4 = M_DIM * K_DIM / 4;

    // XI spans M_DIM * N3 floats (131072 rows x 768 floats) = 402,653,184 B.
    // (R7 bug: was M_DIM*GS*4 = 100MB -> fp16 buffers overlapped XI.)
    const size_t XI_BYTES = (size_t)M_DIM * N3 * 4ul;        // 402,653,184
    const size_t need_gs = XI_BYTES + 67108864ul + 6291456ul; // 476,053,504
    const size_t need_o  = 341835776ul;                       // round-3 layout

    if (ws_size >= need_gs) {
        float* XI = (float*)ws;
        _Float16* XHI = (_Float16*)(ws + XI_BYTES);
        _Float16* XLO = (_Float16*)(ws + XI_BYTES + 33554432ul);
        _Float16* WTH = (_Float16*)(ws + XI_BYTES + 67108864ul);
        _Float16* WTL = (_Float16*)(ws + XI_BYTES + 70254592ul);

        convert_x<<<n4 / 256, 256, 0, stream>>>(
            (const float4*)x, (half4v*)XHI, (half4v*)XLO, n4);
        convert_wt_t<<<384, 256, 0, stream>>>(kz, kr, kh, WTH, WTL);
        dim3 grid(N3 / 128, M_DIM / 128);                   // 24 x 256
        gemm_mfma_split<1><<<grid, 256, 0, stream>>>(
            XHI, XLO, WTH, WTL, XI, nullptr, nullptr);
        scan_gs<<<256, 256, 0, stream>>>(XI, out, mz, mr, br, bz);
    } else if (ws_size >= need_o) {
        float* XZ = (float*)ws;                            // 128 MiB
        float* XR = (float*)(ws + 134217728ul);            // 128 MiB
        _Float16* XHI = (_Float16*)(ws + 268435456ul);     // 32 MiB
        _Float16* XLO = (_Float16*)(ws + 301989888ul);     // 32 MiB
        _Float16* WTH = (_Float16*)(ws + 335544320ul);     // 3 MiB
        _Float16* WTL = (_Float16*)(ws + 338690048ul);     // 3 MiB

        convert_x<<<n4 / 256, 256, 0, stream>>>(
            (const float4*)x, (half4v*)XHI, (half4v*)XLO, n4);
        convert_wt_t<<<384, 256, 0, stream>>>(kz, kr, kh, WTH, WTL);
        dim3 grid(N3 / 128, M_DIM / 128);
        gemm_mfma_split<0><<<grid, 256, 0, stream>>>(
            XHI, XLO, WTH, WTL, XZ, XR, out);
        scan_kernel<<<(64 * H_DIM) / 256, 256, 0, stream>>>(
            XZ, XR, out, mz, mr, br, bz);
    } else {
        float* XZ = (float*)ws;
        float* XR = (float*)(ws + 134217728ul);
        dim3 grid(H_DIM / BN, M_DIM / BM);
        gemm_f32<<<grid, 256, 0, stream>>>(x, kz, XZ,  M_DIM, H_DIM, K_DIM);
        gemm_f32<<<grid, 256, 0, stream>>>(x, kr, XR,  M_DIM, H_DIM, K_DIM);
        gemm_f32<<<grid, 256, 0, stream>>>(x, kh, out, M_DIM, H_DIM, K_DIM);
        scan_kernel<<<(64 * H_DIM) / 256, 256, 0, stream>>>(
            XZ, XR, out, mz, mr, br, bz);
    }
}

// Round 9
// 582.206 us; speedup vs baseline: 1.0231x; 1.0231x over previous
//
#include <hip/hip_runtime.h>
#include <hip/hip_bf16.h>
#include <math.h>

// ---------------------------------------------------------------------------
// GRU-like cell. B=64, T=512, D=512, H=1024 (fp32).
// Round 10:
//   * KEY INSIGHT: measured absmax 2^-8 is the harness's bf16 OUTPUT
//     quantization floor (ulp at 1.0), not our compute error -> ~5x real
//     headroom to the 2e-2 threshold. Intermediates can be fp16.
//   * XI (xz/xr/xh) stored fp16 gate-sliced [b][hh][t][3][256]:
//     GEMM write 393->197 MB, scan read 402->201 MB. Scan was byte-bound
//     (3 read layouts all null at ~2.2 TB/s realized) -> ~90us saved.
//   * Error model: dxh ~ 5e-4*|v| (<2e-3), per-step dh ~ 1e-3, recurrence
//     gain < 1 statistically -> absmax ~5-9e-3 < 2e-2.
//   * GEMM core/structure and scan math unchanged (round-0 GEMM at its
//     structure ceiling ~1.0 PF eff; rcp+NR sigmoid-form scan).
// ---------------------------------------------------------------------------

#define M_DIM 32768   // B*T
#define K_DIM 512     // D
#define H_DIM 1024
#define N3    3072    // 3*H
#define GS    768     // gate-sliced row: 3*256 elems per (b,hh,t)

typedef _Float16 half8v __attribute__((ext_vector_type(8)));
typedef _Float16 half4v __attribute__((ext_vector_type(4)));
typedef float f32x4 __attribute__((ext_vector_type(4)));

__device__ __forceinline__ f32x4 mfma16(half8v a, half8v b, f32x4 c) {
    return __builtin_amdgcn_mfma_f32_16x16x32_f16(a, b, c, 0, 0, 0);
}

__device__ __forceinline__ void load_lds16(const void* g, void* l) {
    __builtin_amdgcn_global_load_lds(
        (const __attribute__((address_space(1))) void*)g,
        (__attribute__((address_space(3))) void*)l, 16, 0, 0);
}

// ---------------------------------------------------------------------------
// Conversion: x [M,K] fp32 -> xhi/xlo fp16 (same layout), via float4.
// ---------------------------------------------------------------------------
__global__ __launch_bounds__(256) void convert_x(
    const float4* __restrict__ x4, half4v* __restrict__ hi4,
    half4v* __restrict__ lo4, int n4)
{
    int i = blockIdx.x * 256 + threadIdx.x;
    if (i >= n4) return;
    float4 v = x4[i];
    half4v h, lo;
    h.x = (_Float16)v.x; lo.x = (_Float16)(v.x - (float)h.x);
    h.y = (_Float16)v.y; lo.y = (_Float16)(v.y - (float)h.y);
    h.z = (_Float16)v.z; lo.z = (_Float16)(v.z - (float)h.z);
    h.w = (_Float16)v.w; lo.w = (_Float16)(v.w - (float)h.w);
    hi4[i] = h; lo4[i] = lo;
}

// ---------------------------------------------------------------------------
// Weights [K,1024] fp32 -> transposed hi/lo fp16 [3][1024][512].
// LDS-tiled 64x64 transpose: coalesced reads AND writes.
// ---------------------------------------------------------------------------
__global__ __launch_bounds__(256) void convert_wt_t(
    const float* __restrict__ kz, const float* __restrict__ kr,
    const float* __restrict__ kh, _Float16* __restrict__ wth,
    _Float16* __restrict__ wtl)
{
    __shared__ float lds[64][65];
    const int bid = blockIdx.x;          // 3 * 8 * 16 = 384
    const int w = bid >> 7;              // weight select
    const int rem = bid & 127;
    const int k0 = (rem >> 4) * 64;
    const int n0 = (rem & 15) * 64;
    const int tid = threadIdx.x;
    const float* s = (w == 0) ? kz : ((w == 1) ? kr : kh);

#pragma unroll
    for (int r = 0; r < 4; ++r) {
        const int kk = (tid >> 4) + r * 16;
        const int nn = (tid & 15) * 4;
        float4 v = *(const float4*)&s[(size_t)(k0 + kk) * H_DIM + n0 + nn];
        lds[kk][nn + 0] = v.x; lds[kk][nn + 1] = v.y;
        lds[kk][nn + 2] = v.z; lds[kk][nn + 3] = v.w;
    }
    __syncthreads();
#pragma unroll
    for (int r = 0; r < 4; ++r) {
        const int nr = (tid >> 4) + r * 16;
        const int kb = (tid & 15) * 4;
        half4v hi, lo;
#pragma unroll
        for (int i = 0; i < 4; ++i) {
            float v = lds[kb + i][nr];
            _Float16 h = (_Float16)v;
            hi[i] = h; lo[i] = (_Float16)(v - (float)h);
        }
        const size_t o = ((size_t)(w * H_DIM + n0 + nr)) * K_DIM + k0 + kb;
        *(half4v*)&wth[o] = hi;
        *(half4v*)&wtl[o] = lo;
    }
}

// ---------------------------------------------------------------------------
// MFMA GEMM: C[M,3072] = A[M,512] * Bt[3072,512]^T with fp16 3-term split.
// Round-0 structure verbatim: 128x128 block tile, 4 waves each 64x64.
// LAYOUT=0: fp32 outputs, three dsts, row stride H_DIM (mid-tier path).
// LAYOUT=1: fp16 gate-sliced XI[b][hh][t][3][256]; XZ arg carries XI ptr.
// ---------------------------------------------------------------------------
template<int LAYOUT>
__global__ __launch_bounds__(256) void gemm_mfma_split(
    const _Float16* __restrict__ Ahi, const _Float16* __restrict__ Alo,
    const _Float16* __restrict__ Bthi, const _Float16* __restrict__ Btlo,
    float* __restrict__ XZ, float* __restrict__ XR, float* __restrict__ OUT)
{
    __shared__ _Float16 Ah[128 * 32];
    __shared__ _Float16 Al[128 * 32];
    __shared__ _Float16 Bh[128 * 32];
    __shared__ _Float16 Bl[128 * 32];

    const int tid = threadIdx.x;
    const int w = tid >> 6, l = tid & 63;
    const int l15 = l & 15, quad = l >> 4;
    const int bx = blockIdx.x, by = blockIdx.y;
    const long m0 = (long)by * 128;
    const long n0 = (long)bx * 128;

    f32x4 acc[4][4] = {};

    // staging: 512 16B-slots per tile, thread covers slots tid and tid+256.
    const int s1 = tid, s2 = tid + 256;
    const long aoff1 = (m0 + (s1 >> 2)) * K_DIM + (s1 & 3) * 8;
    const long aoff2 = (m0 + (s2 >> 2)) * K_DIM + (s2 & 3) * 8;
    const long boff1 = (n0 + (s1 >> 2)) * K_DIM + (s1 & 3) * 8;
    const long boff2 = (n0 + (s2 >> 2)) * K_DIM + (s2 & 3) * 8;

    const _Float16* a1 = Ahi + aoff1;  const _Float16* a2 = Ahi + aoff2;
    const _Float16* q1 = Alo + aoff1;  const _Float16* q2 = Alo + aoff2;
    const _Float16* b1 = Bthi + boff1; const _Float16* b2 = Bthi + boff2;
    const _Float16* c1 = Btlo + boff1; const _Float16* c2 = Btlo + boff2;

    _Float16* ldsA1 = &Ah[w * 512]; _Float16* ldsA2 = &Ah[2048 + w * 512];
    _Float16* ldsQ1 = &Al[w * 512]; _Float16* ldsQ2 = &Al[2048 + w * 512];
    _Float16* ldsB1 = &Bh[w * 512]; _Float16* ldsB2 = &Bh[2048 + w * 512];
    _Float16* ldsC1 = &Bl[w * 512]; _Float16* ldsC2 = &Bl[2048 + w * 512];

    const int wm = (w >> 1) * 64, wn = (w & 1) * 64;

    for (int kk = 0; kk < K_DIM / 32; ++kk) {
        load_lds16(a1, ldsA1); load_lds16(a2, ldsA2);
        load_lds16(q1, ldsQ1); load_lds16(q2, ldsQ2);
        load_lds16(b1, ldsB1); load_lds16(b2, ldsB2);
        load_lds16(c1, ldsC1); load_lds16(c2, ldsC2);
        a1 += 32; a2 += 32; q1 += 32; q2 += 32;
        b1 += 32; b2 += 32; c1 += 32; c2 += 32;
        __syncthreads();

        half8v afh[4], afl[4], bfh[4], bfl[4];
#pragma unroll
        for (int mi = 0; mi < 4; ++mi) {
            int row = (wm + mi * 16 + l15) * 32 + quad * 8;
            afh[mi] = *(const half8v*)&Ah[row];
            afl[mi] = *(const half8v*)&Al[row];
        }
#pragma unroll
        for (int ni = 0; ni < 4; ++ni) {
            int row = (wn + ni * 16 + l15) * 32 + quad * 8;
            bfh[ni] = *(const half8v*)&Bh[row];
            bfl[ni] = *(const half8v*)&Bl[row];
        }
#pragma unroll
        for (int mi = 0; mi < 4; ++mi)
#pragma unroll
            for (int ni = 0; ni < 4; ++ni) {
                acc[mi][ni] = mfma16(afh[mi], bfh[ni], acc[mi][ni]);
                acc[mi][ni] = mfma16(afh[mi], bfl[ni], acc[mi][ni]);
                acc[mi][ni] = mfma16(afl[mi], bfh[ni], acc[mi][ni]);
            }
        __syncthreads();
    }

    // Epilogue: C/D layout col=lane&15, row=quad*4+i.
    if (LAYOUT == 0) {
        float* dst = (bx < 8) ? XZ : ((bx < 16) ? XR : OUT);
        const long nl = (long)(bx & 7) * 128 + wn + l15;
#pragma unroll
        for (int mi = 0; mi < 4; ++mi) {
            const long m = m0 + wm + mi * 16 + quad * 4;
#pragma unroll
            for (int ni = 0; ni < 4; ++ni) {
                float* p = dst + m * H_DIM + nl + ni * 16;
#pragma unroll
                for (int i = 0; i < 4; ++i)
                    p[(long)i * H_DIM] = acc[mi][ni][i];
            }
        }
    } else {
        // fp16 gate-sliced: XI[b][hh][t][gate][256]; n>>8 constant per tile
        // (nlo+ni*16 <= 255, never carries into hh).
        _Float16* XI = (_Float16*)XZ;
        const int gate = bx >> 3;                    // 0=z 1=r 2=h
        const long n   = (long)(bx & 7) * 128 + wn + l15;
        const long hh  = n >> 8;
        const long nlo = n & 255;
#pragma unroll
        for (int mi = 0; mi < 4; ++mi) {
            const long m = m0 + wm + mi * 16 + quad * 4;
            const long b = m >> 9;
            const long t = m & 511;
            _Float16* p = XI + ((b * 4 + hh) * 512 + t) * GS + gate * 256 + nlo;
#pragma unroll
            for (int ni = 0; ni < 4; ++ni) {
#pragma unroll
                for (int i = 0; i < 4; ++i)
                    p[(long)i * GS + ni * 16] = (_Float16)acc[mi][ni][i];
            }
        }
    }
}

// ---------------------------------------------------------------------------
// Fallback fp32 GEMM (round 0)
// ---------------------------------------------------------------------------
#define BM 128
#define BN 128
#define BK 8
__global__ __launch_bounds__(256) void gemm_f32(
    const float* __restrict__ A, const float* __restrict__ B,
    float* __restrict__ C, int M, int N, int K)
{
    __shared__ float As[BK][BM];
    __shared__ float Bs[BK][BN];
    const int tid = threadIdx.x;
    const int bm = blockIdx.y * BM, bn = blockIdx.x * BN;
    const int tx = tid & 15, ty = tid >> 4;
    float acc[8][8];
#pragma unroll
    for (int i = 0; i < 8; i++)
#pragma unroll
        for (int j = 0; j < 8; j++) acc[i][j] = 0.f;
    const int a_row = tid >> 1, a_k = (tid & 1) * 4;
    const int b_row = tid >> 5, b_col = (tid & 31) * 4;
    const float* Aptr = A + (size_t)(bm + a_row) * K + a_k;
    const float* Bptr = B + (size_t)b_row * N + bn + b_col;
    for (int k0 = 0; k0 < K; k0 += BK) {
        float4 av = *(const float4*)(Aptr + k0);
        float4 bv = *(const float4*)(Bptr + (size_t)k0 * N);
        As[a_k + 0][a_row] = av.x; As[a_k + 1][a_row] = av.y;
        As[a_k + 2][a_row] = av.z; As[a_k + 3][a_row] = av.w;
        *(float4*)&Bs[b_row][b_col] = bv;
        __syncthreads();
#pragma unroll
        for (int kk = 0; kk < BK; kk++) {
            float4 a0 = *(const float4*)&As[kk][ty * 8];
            float4 a1 = *(const float4*)&As[kk][ty * 8 + 4];
            float4 b0 = *(const float4*)&Bs[kk][tx * 8];
            float4 b1 = *(const float4*)&Bs[kk][tx * 8 + 4];
            float a[8] = {a0.x, a0.y, a0.z, a0.w, a1.x, a1.y, a1.z, a1.w};
            float b[8] = {b0.x, b0.y, b0.z, b0.w, b1.x, b1.y, b1.z, b1.w};
#pragma unroll
            for (int i = 0; i < 8; i++)
#pragma unroll
                for (int j = 0; j < 8; j++)
                    acc[i][j] = fmaf(a[i], b[j], acc[i][j]);
        }
        __syncthreads();
    }
    float* Cptr = C + (size_t)(bm + ty * 8) * N + bn + tx * 8;
#pragma unroll
    for (int i = 0; i < 8; i++) {
        float4 c0 = {acc[i][0], acc[i][1], acc[i][2], acc[i][3]};
        float4 c1 = {acc[i][4], acc[i][5], acc[i][6], acc[i][7]};
        *(float4*)(Cptr + (size_t)i * N)     = c0;
        *(float4*)(Cptr + (size_t)i * N + 4) = c1;
    }
}

// ---------------------------------------------------------------------------
// Scan math (shared): gates in sigmoid form; divisions via v_rcp + 1 Newton.
// ---------------------------------------------------------------------------
__device__ __forceinline__ float vrcp_nr(float d) {
    float r = __builtin_amdgcn_rcpf(d);
    return r * fmaf(-d, r, 2.0f);     // Newton: r*(2 - d*r)
}

// ---------------------------------------------------------------------------
// Gate-sliced fp16 scan: block (b,hh) streams XI[b][hh][t][3][256] halves
// (1.5KB contiguous per t). Math identical to round 3 (inputs now fp16).
// Writes out[b][t][h] fp32.
// ---------------------------------------------------------------------------
__global__ __launch_bounds__(256) void scan_gs(
    const _Float16* __restrict__ XI, float* __restrict__ out,
    const float* __restrict__ mz, const float* __restrict__ mr,
    const float* __restrict__ br, const float* __restrict__ bz)
{
    const int bid = blockIdx.x;            // 256 = 64 b * 4 hh
    const int b = bid >> 2, hh = bid & 3;
    const int tid = threadIdx.x;
    const int h = hh * 256 + tid;

    const float mzK = -mz[h];
    const float mrK = -2.0f * mr[h];
    const float bzK = -bz[h];
    const float brK = -2.0f * br[h];
    float hs = 0.f;

    const _Float16* base = XI + ((size_t)(b * 4 + hh) * 512) * GS + tid;
    float* const po = out + ((size_t)b << 19) + h;     // b*512*1024 + h

    float cz[16], cr[16], ch[16];
#pragma unroll
    for (int j = 0; j < 16; ++j) {
        const _Float16* p = base + (size_t)j * GS;
        cz[j] = bzK - (float)p[0];
        cr[j] = fmaf(-2.0f, (float)p[256], brK);
        ch[j] = -2.0f * (float)p[512];
    }
    for (int t0 = 0; t0 < 512; t0 += 16) {
        float nz[16], nr[16], nh[16];
        const bool more = (t0 + 16) < 512;
        if (more) {
            const _Float16* pb = base + (size_t)(t0 + 16) * GS;
#pragma unroll
            for (int j = 0; j < 16; ++j) {
                const _Float16* p = pb + (size_t)j * GS;
                nz[j] = (float)p[0]; nr[j] = (float)p[256]; nh[j] = (float)p[512];
            }
        }
        float* pout = po + ((size_t)t0 << 10);
#pragma unroll
        for (int j = 0; j < 16; ++j) {
            const float u1   = fmaf(hs, mrK, cr[j]);
            const float uz   = fmaf(hs, mzK, cz[j]);
            const float hsK2 = -4.0f * hs;
            const float e1 = __expf(u1);
            const float s1 = vrcp_nr(e1 + 1.0f);
            const float ez = __expf(uz);
            const float sz = vrcp_nr(ez + 1.0f);
            const float u2 = fmaf(s1, hsK2, ch[j]);
            const float e2 = __expf(u2);
            const float s2 = vrcp_nr(e2 + 1.0f);
            const float th = fmaf(2.0f, s2, -1.0f);
            const float hn = fmaf(sz, hs - th, th);
            *pout = hn; pout += H_DIM;
            hs = hn;
        }
        if (more) {
#pragma unroll
            for (int j = 0; j < 16; ++j) {
                cz[j] = bzK - nz[j];
                cr[j] = fmaf(-2.0f, nr[j], brK);
                ch[j] = -2.0f * nh[j];
            }
        }
    }
}

// ---------------------------------------------------------------------------
// OLD scan (round 3), fp32 in-place variant for the mid-tier path.
// ---------------------------------------------------------------------------
__global__ __launch_bounds__(256) void scan_kernel(
    const float* __restrict__ XZ, const float* __restrict__ XR,
    float* __restrict__ OUT,
    const float* __restrict__ mz, const float* __restrict__ mr,
    const float* __restrict__ br, const float* __restrict__ bz)
{
    const int gid = blockIdx.x * blockDim.x + threadIdx.x;
    const int b = gid >> 10;
    const int h = gid & (H_DIM - 1);

    const float mzK = -mz[h];
    const float mrK = -2.0f * mr[h];
    const float bzK = -bz[h];
    const float brK = -2.0f * br[h];
    float hs = 0.f;
    size_t idx = (size_t)b * 512 * H_DIM + h;

    float cz[16], cr[16], ch[16];
#pragma unroll
    for (int j = 0; j < 16; ++j) {
        cz[j] = bzK - XZ[idx + (size_t)j * H_DIM];
        cr[j] = fmaf(-2.0f, XR[idx + (size_t)j * H_DIM], brK);
        ch[j] = -2.0f * OUT[idx + (size_t)j * H_DIM];
    }
    for (int t0 = 0; t0 < 512; t0 += 16) {
        float nz[16], nr[16], nh[16];
        const bool more = (t0 + 16) < 512;
        const size_t nidx = idx + 16ul * H_DIM;
        if (more) {
#pragma unroll
            for (int j = 0; j < 16; ++j) {
                nz[j] = XZ[nidx + (size_t)j * H_DIM];
                nr[j] = XR[nidx + (size_t)j * H_DIM];
                nh[j] = OUT[nidx + (size_t)j * H_DIM];
            }
        }
#pragma unroll
        for (int j = 0; j < 16; ++j) {
            const float u1   = fmaf(hs, mrK, cr[j]);
            const float uz   = fmaf(hs, mzK, cz[j]);
            const float hsK2 = -4.0f * hs;
            const float e1 = __expf(u1);
            const float s1 = vrcp_nr(e1 + 1.0f);
            const float ez = __expf(uz);
            const float sz = vrcp_nr(ez + 1.0f);
            const float u2 = fmaf(s1, hsK2, ch[j]);
            const float e2 = __expf(u2);
            const float s2 = vrcp_nr(e2 + 1.0f);
            const float th = fmaf(2.0f, s2, -1.0f);
            const float hn = fmaf(sz, hs - th, th);
            OUT[idx + (size_t)j * H_DIM] = hn;
            hs = hn;
        }
        idx = nidx;
        if (more) {
#pragma unroll
            for (int j = 0; j < 16; ++j) {
                cz[j] = bzK - nz[j];
                cr[j] = fmaf(-2.0f, nr[j], brK);
                ch[j] = -2.0f * nh[j];
            }
        }
    }
}

// ---------------------------------------------------------------------------
extern "C" void kernel_launch(void* const* d_in, const int* in_sizes, int n_in,
                              void* d_out, int out_size, void* d_ws, size_t ws_size,
                              hipStream_t stream) {
    const float* x  = (const float*)d_in[0];
    const float* kz = (const float*)d_in[1];
    const float* kr = (const float*)d_in[2];
    const float* kh = (const float*)d_in[3];
    const float* mz = (const float*)d_in[4];
    const float* mr = (const float*)d_in[5];
    const float* br = (const float*)d_in[6];
    const float* bz = (const float*)d_in[7];
    float* out = (float*)d_out;

    char* ws = (char*)d_ws;
    const int n4 = M_DIM * K_DIM / 4;

    // XI: fp16, M_DIM * N3 elems = 201,326,592 B.
    const size_t XI_BYTES = (size_t)M_DIM * N3 * 2ul;
    const size_t need_gs = XI_BYTES + 67108864ul + 6291456ul; // ~262 MiB
    const size_t need_o  = 341835776ul;                       // fp32 mid-tier

    if (ws_size >= need_gs) {
        _Float16* XI = (_Float16*)ws;
        _Float16* XHI = (_Float16*)(ws + XI_BYTES);
        _Float16* XLO = (_Float16*)(ws + XI_BYTES + 33554432ul);
        _Float16* WTH = (_Float16*)(ws + XI_BYTES + 67108864ul);
        _Float16* WTL = (_Float16*)(ws + XI_BYTES + 70254592ul);

        convert_x<<<n4 / 256, 256, 0, stream>>>(
            (const float4*)x, (half4v*)XHI, (half4v*)XLO, n4);
        convert_wt_t<<<384, 256, 0, stream>>>(kz, kr, kh, WTH, WTL);
        dim3 grid(N3 / 128, M_DIM / 128);                   // 24 x 256
        gemm_mfma_split<1><<<grid, 256, 0, stream>>>(
            XHI, XLO, WTH, WTL, (float*)XI, nullptr, nullptr);
        scan_gs<<<256, 256, 0, stream>>>(XI, out, mz, mr, br, bz);
    } else if (ws_size >= need_o) {
        float* XZ = (float*)ws;                            // 128 MiB
        float* XR = (float*)(ws + 134217728ul);            // 128 MiB
        _Float16* XHI = (_Float16*)(ws + 268435456ul);     // 32 MiB
        _Float16* XLO = (_Float16*)(ws + 301989888ul);     // 32 MiB
        _Float16* WTH = (_Float16*)(ws + 335544320ul);     // 3 MiB
        _Float16* WTL = (_Float16*)(ws + 338690048ul);     // 3 MiB

        convert_x<<<n4 / 256, 256, 0, stream>>>(
            (const float4*)x, (half4v*)XHI, (half4v*)XLO, n4);
        convert_wt_t<<<384, 256, 0, stream>>>(kz, kr, kh, WTH, WTL);
        dim3 grid(N3 / 128, M_DIM / 128);
        gemm_mfma_split<0><<<grid, 256, 0, stream>>>(
            XHI, XLO, WTH, WTL, XZ, XR, out);
        scan_kernel<<<(64 * H_DIM) / 256, 256, 0, stream>>>(
            XZ, XR, out, mz, mr, br, bz);
    } else {
        float* XZ = (float*)ws;
        float* XR = (float*)(ws + 134217728ul);
        dim3 grid(H_DIM / BN, M_DIM / BM);
        gemm_f32<<<grid, 256, 0, stream>>>(x, kz, XZ,  M_DIM, H_DIM, K_DIM);
        gemm_f32<<<grid, 256, 0, stream>>>(x, kr, XR,  M_DIM, H_DIM, K_DIM);
        gemm_f32<<<grid, 256, 0, stream>>>(x, kh, out, M_DIM, H_DIM, K_DIM);
        scan_kernel<<<(64 * H_DIM) / 256, 256, 0, stream>>>(
            XZ, XR, out, mz, mr, br, bz);
    }
}